// Round 14
// baseline (625.666 us; speedup 1.0000x reference)
//
#include <hip/hip_runtime.h>
#include <hip/hip_fp16.h>
#include <math.h>

#define LEAKY(x) ((x) > 0.f ? (x) : 0.01f * (x))
#define BK_SHIFT 9            // 512 nodes per bucket
#define NBMAX 128             // supports N <= 65536
#define BCAP 16384            // edges capacity per bucket (mean 8192 + ~90 sigma)

__device__ __forceinline__ void add4(float4& acc, const float4& v) {
    acc.x += v.x; acc.y += v.y; acc.z += v.z; acc.w += v.w;
}

// Pass 1 of CSR fill: LDS counting-sort 2048-edge chunks by 512-node bucket,
// reserve per-bucket spans via bfill atomics, flush contiguous runs to tmp
// (fixed-capacity bucket-major: bucket b owns tmp[b*BCAP .. b*BCAP+BCAP)).
__global__ __launch_bounds__(256) void bin_kernel(const int* __restrict__ src,
                                                  const int* __restrict__ dst,
                                                  int* __restrict__ bfill,
                                                  uint2* __restrict__ tmp,
                                                  int E, int nb) {
    __shared__ int hist[NBMAX];
    __shared__ int scanbuf[NBMAX];
    __shared__ int lofs[NBMAX];
    __shared__ int adj[NBMAX];
    __shared__ uint2 buf[2048];
    __shared__ unsigned char bkt_of[2048];
    int base = blockIdx.x * 2048;
    int cnt = min(2048, E - base);
    int tid = threadIdx.x;
    for (int b = tid; b < NBMAX; b += 256) hist[b] = 0;
    __syncthreads();
    int es[8], ed[8];
#pragma unroll
    for (int k = 0; k < 8; ++k) {
        int l = tid + k * 256;
        if (l < cnt) {
            es[k] = src[base + l];
            ed[k] = dst[base + l];
            atomicAdd(&hist[ed[k] >> BK_SHIFT], 1);
        }
    }
    __syncthreads();
    if (tid < NBMAX) scanbuf[tid] = hist[tid];
    __syncthreads();
    for (int off = 1; off < NBMAX; off <<= 1) {
        int t = (tid < NBMAX && tid >= off) ? scanbuf[tid - off] : 0;
        __syncthreads();
        if (tid < NBMAX) scanbuf[tid] += t;
        __syncthreads();
    }
    if (tid < nb) {
        int cb = hist[tid];
        int start = scanbuf[tid] - cb;   // exclusive (position in buf)
        lofs[tid] = start;
        int g = (cb > 0) ? atomicAdd(&bfill[tid], cb) : 0;
        adj[tid] = tid * BCAP + g - start;  // buf idx -> tmp idx shift
    }
    __syncthreads();
#pragma unroll
    for (int k = 0; k < 8; ++k) {
        int l = tid + k * 256;
        if (l < cnt) {
            int b = ed[k] >> BK_SHIFT;
            int r = atomicAdd(&lofs[b], 1);
            buf[r] = make_uint2((unsigned)es[k], (unsigned)ed[k]);
            bkt_of[r] = (unsigned char)b;
        }
    }
    __syncthreads();
    for (int j = tid; j < cnt; j += 256) {
        int b = bkt_of[j];
        tmp[adj[b] + j] = buf[j];
    }
}

// Pass 2: one block per 512-node bucket. Per-node in-degree (LDS hist), local
// scan -> row_ptr, dis = rsqrt(deg+1), layer-0 pre-scale Z0 = dis*x, and the
// final edge scatter with LDS cursors. Everything stays inside one CU.
__global__ __launch_bounds__(512) void place2(const uint2* __restrict__ tmp,
                                              const int* __restrict__ bfill,
                                              const float* __restrict__ X,
                                              float* __restrict__ dis,
                                              int* __restrict__ row_ptr,
                                              int* __restrict__ edge_src,
                                              float* __restrict__ Z0, int kq,
                                              int n, int E, int nb) {
    __shared__ int hist[512];
    __shared__ int sc[512];
    __shared__ int sbf[NBMAX];
    __shared__ int bb_s;
    int b = blockIdx.x;
    int tid = threadIdx.x;
    if (tid < NBMAX) sbf[tid] = (tid < nb) ? bfill[tid] : 0;
    hist[tid] = 0;
    __syncthreads();
    if (tid == 0) {
        int s = 0;
        for (int k = 0; k < b; ++k) s += sbf[k];
        bb_s = s;
    }
    __syncthreads();
    int bb = bb_s;
    int cnt = sbf[b];
    const uint2* mybkt = tmp + (size_t)b * BCAP;
    int node0 = b << BK_SHIFT;
    for (int j = tid; j < cnt; j += 512)
        atomicAdd(&hist[(int)mybkt[j].y - node0], 1);
    __syncthreads();
    int v = hist[tid];
    sc[tid] = v;
    __syncthreads();
    for (int off = 1; off < 512; off <<= 1) {
        int t = (tid >= off) ? sc[tid - off] : 0;
        __syncthreads();
        sc[tid] += t;
        __syncthreads();
    }
    int excl = sc[tid] - v;
    int i = node0 + tid;
    if (i < n) {
        row_ptr[i] = bb + excl;
        float di = rsqrtf((float)(v + 1));  // +1: self-loop
        dis[i] = di;
        const float4* X4 = (const float4*)X;
        float4* Z4 = (float4*)Z0;
        for (int j = 0; j < kq; ++j) {
            float4 xv = X4[(size_t)i * kq + j];
            Z4[(size_t)i * kq + j] = make_float4(di * xv.x, di * xv.y, di * xv.z, di * xv.w);
        }
    }
    if (b == 0 && tid == 0) row_ptr[n] = E;
    __syncthreads();
    hist[tid] = bb + excl;  // reuse as LDS cursor
    __syncthreads();
    for (int j = tid; j < cnt; j += 512) {
        uint2 ev = mybkt[j];
        int pos = atomicAdd(&hist[(int)ev.y - node0], 1);
        edge_src[pos] = (int)ev.x;
    }
}

// ---------- Fused GCN layer (96-wide, fp16 input) ----------
// Phase 1: 4 waves x 16 nodes sequential, wave-per-node gather (8 edge-groups x
// 8 feature-lanes x 12 halves), fp32 butterfly; lanes g==0 write di-scaled agg
// rows into LDS A-tile. Sum-of-16-degrees balance -> barrier imbalance ~6%.
// Phase 2: R13 gemm (192 threads, 8 rows x 3 f4-cols/thread, W coalesced from
// global). SCALE: multiply by dis (next Z); OUTH: fp16 out else fp32.
template <bool SCALE, bool OUTH>
__global__ __launch_bounds__(256) void fused_h(const __half* __restrict__ Zh,
                                               const float* __restrict__ dis,
                                               const int* __restrict__ row_ptr,
                                               const int* __restrict__ edge_src,
                                               const float* __restrict__ W,
                                               const float* __restrict__ b,
                                               void* __restrict__ Y, int n) {
    __shared__ __align__(16) float Al[64 * 96];
    int tid = threadIdx.x;
    int i0 = blockIdx.x * 64;
    int w = tid >> 6, lane = tid & 63;
    int g = lane >> 3, c = lane & 7;
    for (int t = 0; t < 16; ++t) {
        int nl = w * 16 + t;
        int i = i0 + nl;
        if (i < n) {
            float di = dis[i];
            float acc[12];
            if (g == 0) {
                const uint2* zp = (const uint2*)(Zh + (size_t)i * 96 + c * 12);
#pragma unroll
                for (int k = 0; k < 3; ++k) {
                    uint2 u = zp[k];
                    float2 f0 = __half22float2(*(const __half2*)&u.x);
                    float2 f1 = __half22float2(*(const __half2*)&u.y);
                    acc[k * 4 + 0] = f0.x; acc[k * 4 + 1] = f0.y;
                    acc[k * 4 + 2] = f1.x; acc[k * 4 + 3] = f1.y;
                }
            } else {
#pragma unroll
                for (int k = 0; k < 12; ++k) acc[k] = 0.f;
            }
            int re0 = row_ptr[i], re1 = row_ptr[i + 1];
#pragma unroll 4
            for (int e = re0 + g; e < re1; e += 8) {
                int s = edge_src[e];
                const uint2* zp = (const uint2*)(Zh + (size_t)s * 96 + c * 12);
                uint2 u0 = zp[0], u1 = zp[1], u2 = zp[2];
                float2 f;
                f = __half22float2(*(const __half2*)&u0.x); acc[0] += f.x; acc[1] += f.y;
                f = __half22float2(*(const __half2*)&u0.y); acc[2] += f.x; acc[3] += f.y;
                f = __half22float2(*(const __half2*)&u1.x); acc[4] += f.x; acc[5] += f.y;
                f = __half22float2(*(const __half2*)&u1.y); acc[6] += f.x; acc[7] += f.y;
                f = __half22float2(*(const __half2*)&u2.x); acc[8] += f.x; acc[9] += f.y;
                f = __half22float2(*(const __half2*)&u2.y); acc[10] += f.x; acc[11] += f.y;
            }
#pragma unroll
            for (int m = 8; m < 64; m <<= 1) {
#pragma unroll
                for (int k = 0; k < 12; ++k) acc[k] += __shfl_xor(acc[k], m);
            }
            if (g == 0) {
                float4* ap = (float4*)&Al[nl * 96 + c * 12];
#pragma unroll
                for (int k = 0; k < 3; ++k)
                    ap[k] = make_float4(di * acc[k * 4 + 0], di * acc[k * 4 + 1],
                                        di * acc[k * 4 + 2], di * acc[k * 4 + 3]);
            }
        } else if (g == 0) {
            float4* ap = (float4*)&Al[nl * 96 + c * 12];
#pragma unroll
            for (int k = 0; k < 3; ++k) ap[k] = make_float4(0.f, 0.f, 0.f, 0.f);
        }
    }
    __syncthreads();
    if (tid >= 192) return;
    int fq = tid % 24;
    int rg = tid / 24;
    const float4* W4 = (const float4*)W;
    float4 bb = ((const float4*)b)[fq];
    float4 acc[8];
#pragma unroll
    for (int r = 0; r < 8; ++r) acc[r] = bb;
    for (int kc = 0; kc < 96; kc += 8) {
        float4 wv[8];
#pragma unroll
        for (int kk = 0; kk < 8; ++kk) wv[kk] = W4[(size_t)(kc + kk) * 24 + fq];
#pragma unroll
        for (int r = 0; r < 8; ++r) {
            const float4* ar = (const float4*)&Al[(rg * 8 + r) * 96 + kc];
#pragma unroll
            for (int k4 = 0; k4 < 2; ++k4) {
                float4 a = ar[k4];
                float4 w0 = wv[4 * k4 + 0], w1 = wv[4 * k4 + 1];
                float4 w2 = wv[4 * k4 + 2], w3 = wv[4 * k4 + 3];
                acc[r].x += a.x * w0.x + a.y * w1.x + a.z * w2.x + a.w * w3.x;
                acc[r].y += a.x * w0.y + a.y * w1.y + a.z * w2.y + a.w * w3.y;
                acc[r].z += a.x * w0.z + a.y * w1.z + a.z * w2.z + a.w * w3.z;
                acc[r].w += a.x * w0.w + a.y * w1.w + a.z * w2.w + a.w * w3.w;
            }
        }
    }
#pragma unroll
    for (int r = 0; r < 8; ++r) {
        int gi = i0 + rg * 8 + r;
        if (gi < n) {
            float4 o;
            o.x = LEAKY(acc[r].x); o.y = LEAKY(acc[r].y);
            o.z = LEAKY(acc[r].z); o.w = LEAKY(acc[r].w);
            if (SCALE) {
                float di = dis[gi];
                o.x *= di; o.y *= di; o.z *= di; o.w *= di;
            }
            if (OUTH) {
                __half2 h0 = __floats2half2_rn(o.x, o.y);
                __half2 h1 = __floats2half2_rn(o.z, o.w);
                uint2 u;
                u.x = *(unsigned*)&h0;
                u.y = *(unsigned*)&h1;
                ((uint2*)Y)[(size_t)gi * 24 + fq] = u;
            } else {
                ((float4*)Y)[(size_t)gi * 24 + fq] = o;
            }
        }
    }
}

// ---------- Fused layer 0 (16-wide fp32 input -> fp16 out) ----------
// Gather: 16 edge-groups x 4 feature-lanes (float4 each); gemm<16> phase.
__global__ __launch_bounds__(256) void fused_l0(const float* __restrict__ Z0,
                                                const float* __restrict__ dis,
                                                const int* __restrict__ row_ptr,
                                                const int* __restrict__ edge_src,
                                                const float* __restrict__ W,
                                                const float* __restrict__ b,
                                                __half* __restrict__ Y, int n) {
    __shared__ __align__(16) float Al[64 * 16];
    int tid = threadIdx.x;
    int i0 = blockIdx.x * 64;
    int w = tid >> 6, lane = tid & 63;
    int g = lane >> 2, c = lane & 3;
    const float4* Z4 = (const float4*)Z0;
    for (int t = 0; t < 16; ++t) {
        int nl = w * 16 + t;
        int i = i0 + nl;
        if (i < n) {
            float di = dis[i];
            float4 acc;
            if (g == 0) acc = Z4[(size_t)i * 4 + c];
            else acc = make_float4(0.f, 0.f, 0.f, 0.f);
            int re0 = row_ptr[i], re1 = row_ptr[i + 1];
#pragma unroll 2
            for (int e = re0 + g; e < re1; e += 16) {
                int s = edge_src[e];
                add4(acc, Z4[(size_t)s * 4 + c]);
            }
#pragma unroll
            for (int m = 4; m < 64; m <<= 1) {
                acc.x += __shfl_xor(acc.x, m);
                acc.y += __shfl_xor(acc.y, m);
                acc.z += __shfl_xor(acc.z, m);
                acc.w += __shfl_xor(acc.w, m);
            }
            if (g == 0)
                *(float4*)&Al[nl * 16 + c * 4] =
                    make_float4(di * acc.x, di * acc.y, di * acc.z, di * acc.w);
        } else if (g == 0) {
            *(float4*)&Al[nl * 16 + c * 4] = make_float4(0.f, 0.f, 0.f, 0.f);
        }
    }
    __syncthreads();
    if (tid >= 192) return;
    int fq = tid % 24;
    int rg = tid / 24;
    const float4* W4 = (const float4*)W;
    float4 bb = ((const float4*)b)[fq];
    float4 acc[8];
#pragma unroll
    for (int r = 0; r < 8; ++r) acc[r] = bb;
    for (int kc = 0; kc < 16; kc += 8) {
        float4 wv[8];
#pragma unroll
        for (int kk = 0; kk < 8; ++kk) wv[kk] = W4[(size_t)(kc + kk) * 24 + fq];
#pragma unroll
        for (int r = 0; r < 8; ++r) {
            const float4* ar = (const float4*)&Al[(rg * 8 + r) * 16 + kc];
#pragma unroll
            for (int k4 = 0; k4 < 2; ++k4) {
                float4 a = ar[k4];
                float4 w0 = wv[4 * k4 + 0], w1 = wv[4 * k4 + 1];
                float4 w2 = wv[4 * k4 + 2], w3 = wv[4 * k4 + 3];
                acc[r].x += a.x * w0.x + a.y * w1.x + a.z * w2.x + a.w * w3.x;
                acc[r].y += a.x * w0.y + a.y * w1.y + a.z * w2.y + a.w * w3.y;
                acc[r].z += a.x * w0.z + a.y * w1.z + a.z * w2.z + a.w * w3.z;
                acc[r].w += a.x * w0.w + a.y * w1.w + a.z * w2.w + a.w * w3.w;
            }
        }
    }
#pragma unroll
    for (int r = 0; r < 8; ++r) {
        int gi = i0 + rg * 8 + r;
        if (gi < n) {
            float di = dis[gi];
            float4 o;
            o.x = di * LEAKY(acc[r].x); o.y = di * LEAKY(acc[r].y);
            o.z = di * LEAKY(acc[r].z); o.w = di * LEAKY(acc[r].w);
            __half2 h0 = __floats2half2_rn(o.x, o.y);
            __half2 h1 = __floats2half2_rn(o.z, o.w);
            uint2 u;
            u.x = *(unsigned*)&h0;
            u.y = *(unsigned*)&h1;
            ((uint2*)Y)[(size_t)gi * 24 + fq] = u;
        }
    }
}

__device__ __forceinline__ int lower_bound(const int* b, int n, int v) {
    int lo = 0, hi = n;
    while (lo < hi) {
        int m = (lo + hi) >> 1;
        if (b[m] < v) lo = m + 1; else hi = m;
    }
    return lo;
}

// grid = G*8, block = 96. Chunked per-graph partial max/sum.
__global__ void pool_partial(const float* __restrict__ X, const int* __restrict__ batch,
                             float* __restrict__ pmax, float* __restrict__ psum, int n) {
    int g = blockIdx.x / 8, ch = blockIdx.x % 8;
    int f = threadIdx.x;
    int s = lower_bound(batch, n, g), e = lower_bound(batch, n, g + 1);
    int len = e - s;
    int cs = s + (int)((long)len * ch / 8);
    int ce = s + (int)((long)len * (ch + 1) / 8);
    float mx = -INFINITY, sm = 0.f;
    for (int i = cs; i < ce; ++i) {
        float v = X[(size_t)i * 96 + f];
        mx = fmaxf(mx, v);
        sm += v;
    }
    pmax[(size_t)blockIdx.x * 96 + f] = mx;
    psum[(size_t)blockIdx.x * 96 + f] = sm;
}

// Merged pool_reduce + MLP head: grid = G, block = 96.
__global__ void pool_final(const float* __restrict__ pmax, const float* __restrict__ psum,
                           const int* __restrict__ batch,
                           const float* __restrict__ Wo1, const float* __restrict__ bo1,
                           const float* __restrict__ Wo2, const float* __restrict__ bo2,
                           float* __restrict__ out, int n) {
    __shared__ float pooled[192];
    __shared__ float sh[96];
    int g = blockIdx.x, f = threadIdx.x;
    float mx = -INFINITY, sm = 0.f;
    for (int c = 0; c < 8; ++c) {
        mx = fmaxf(mx, pmax[(size_t)(g * 8 + c) * 96 + f]);
        sm += psum[(size_t)(g * 8 + c) * 96 + f];
    }
    int s = lower_bound(batch, n, g), e = lower_bound(batch, n, g + 1);
    float cnt = fmaxf((float)(e - s), 1.f);
    pooled[f] = mx;
    pooled[96 + f] = sm / cnt;
    __syncthreads();
    float acc = bo1[f];
    for (int k = 0; k < 192; ++k) acc += pooled[k] * Wo1[k * 96 + f];
    float a = LEAKY(acc);
    sh[f] = a * Wo2[f];
    __syncthreads();
    if (f == 0) {
        float sacc = 0.f;
        for (int k = 0; k < 96; ++k) sacc += sh[k];
        out[g] = sacc + bo2[0];
    }
}

extern "C" void kernel_launch(void* const* d_in, const int* in_sizes, int n_in,
                              void* d_out, int out_size, void* d_ws, size_t ws_size,
                              hipStream_t stream) {
    const float* x      = (const float*)d_in[0];
    const int*   eidx   = (const int*)d_in[1];
    const int*   batch  = (const int*)d_in[2];
    const float* W_init = (const float*)d_in[3];
    const float* b_init = (const float*)d_in[4];
    const float* W1 = (const float*)d_in[5];  const float* b1 = (const float*)d_in[6];
    const float* W2 = (const float*)d_in[7];  const float* b2 = (const float*)d_in[8];
    const float* W3 = (const float*)d_in[9];  const float* b3 = (const float*)d_in[10];
    const float* W4 = (const float*)d_in[11]; const float* b4 = (const float*)d_in[12];
    const float* Wo1 = (const float*)d_in[13]; const float* bo1 = (const float*)d_in[14];
    const float* Wo2 = (const float*)d_in[15]; const float* bo2 = (const float*)d_in[16];
    float* out = (float*)d_out;

    const int N = in_sizes[2];
    const int E = in_sizes[1] / 2;
    const int G = out_size;
    const int* src = eidx;
    const int* dst = eidx + E;

    char* ws = (char*)d_ws;
    size_t off = 0;
    auto alloc = [&](size_t bytes) {
        size_t o = off;
        off += (bytes + 255) & ~(size_t)255;
        return o;
    };
    float* dis       = (float*)(ws + alloc((size_t)N * 4));
    int*   row_ptr   = (int*)(ws + alloc((size_t)(N + 1) * 4));
    int*   bfill     = (int*)(ws + alloc(NBMAX * 4));
    int*   edge_src  = (int*)(ws + alloc((size_t)E * 4));
    float* Z0        = (float*)(ws + alloc((size_t)N * 16 * 4));
    __half* ZA       = (__half*)(ws + alloc((size_t)N * 96 * 2));
    __half* ZB       = (__half*)(ws + alloc((size_t)N * 96 * 2));
    float* H         = (float*)(ws + alloc((size_t)N * 96 * 4));
    float* pmax      = (float*)(ws + alloc((size_t)G * 8 * 96 * 4));
    float* psum      = (float*)(ws + alloc((size_t)G * 8 * 96 * 4));
    uint2* tmp       = (uint2*)H;  // 12.8 MB < 19.2 MB; bin/place2 end before H written
    (void)ws_size; (void)n_in;

    const int nbBkt  = (N + (1 << BK_SHIFT) - 1) >> BK_SHIFT;
    const int nbTile = (N + 63) / 64;

    hipMemsetAsync(bfill, 0, NBMAX * 4, stream);
    bin_kernel<<<(E + 2047) / 2048, 256, 0, stream>>>(src, dst, bfill, tmp, E, nbBkt);
    place2<<<nbBkt, 512, 0, stream>>>(tmp, bfill, x, dis, row_ptr, edge_src, Z0,
                                      4, N, E, nbBkt);

    // Layer 0 fused: gather 16-wide fp32 + GEMM -> fp16 Z1.
    fused_l0<<<nbTile, 256, 0, stream>>>(Z0, dis, row_ptr, edge_src, W_init, b_init, ZA, N);

    const float* Ws[4] = {W1, W2, W3, W4};
    const float* bs[4] = {b1, b2, b3, b4};
    __half* cur = ZA;
    __half* nxt = ZB;
    for (int l = 0; l < 4; ++l) {
        if (l < 3) {
            fused_h<true, true><<<nbTile, 256, 0, stream>>>(cur, dis, row_ptr, edge_src,
                                                            Ws[l], bs[l], nxt, N);
            __half* t = cur; cur = nxt; nxt = t;
        } else {  // last layer: fp32 unscaled H for pooling
            fused_h<false, false><<<nbTile, 256, 0, stream>>>(cur, dis, row_ptr, edge_src,
                                                              Ws[l], bs[l], H, N);
        }
    }

    pool_partial<<<G * 8, 96, 0, stream>>>(H, batch, pmax, psum, N);
    pool_final<<<G, 96, 0, stream>>>(pmax, psum, batch, Wo1, bo1, Wo2, bo2, out, N);
}

// Round 15
// 480.433 us; speedup vs baseline: 1.3023x; 1.3023x over previous
//
#include <hip/hip_runtime.h>
#include <hip/hip_fp16.h>
#include <math.h>

#define LEAKY(x) ((x) > 0.f ? (x) : 0.01f * (x))
#define BK_SHIFT 9            // 512 nodes per bucket
#define NBMAX 128             // supports N <= 65536
#define BCAP 16384            // edges capacity per bucket (mean 8192 + ~90 sigma)

__device__ __forceinline__ void add4(float4& acc, const float4& v) {
    acc.x += v.x; acc.y += v.y; acc.z += v.z; acc.w += v.w;
}

// Pass 1 of CSR fill: LDS counting-sort 2048-edge chunks by 512-node bucket,
// reserve per-bucket spans via bfill atomics, flush contiguous runs to tmp
// (fixed-capacity bucket-major: bucket b owns tmp[b*BCAP .. b*BCAP+BCAP)).
__global__ __launch_bounds__(256) void bin_kernel(const int* __restrict__ src,
                                                  const int* __restrict__ dst,
                                                  int* __restrict__ bfill,
                                                  uint2* __restrict__ tmp,
                                                  int E, int nb) {
    __shared__ int hist[NBMAX];
    __shared__ int scanbuf[NBMAX];
    __shared__ int lofs[NBMAX];
    __shared__ int adj[NBMAX];
    __shared__ uint2 buf[2048];
    __shared__ unsigned char bkt_of[2048];
    int base = blockIdx.x * 2048;
    int cnt = min(2048, E - base);
    int tid = threadIdx.x;
    for (int b = tid; b < NBMAX; b += 256) hist[b] = 0;
    __syncthreads();
    int es[8], ed[8];
#pragma unroll
    for (int k = 0; k < 8; ++k) {
        int l = tid + k * 256;
        if (l < cnt) {
            es[k] = src[base + l];
            ed[k] = dst[base + l];
            atomicAdd(&hist[ed[k] >> BK_SHIFT], 1);
        }
    }
    __syncthreads();
    if (tid < NBMAX) scanbuf[tid] = hist[tid];
    __syncthreads();
    for (int off = 1; off < NBMAX; off <<= 1) {
        int t = (tid < NBMAX && tid >= off) ? scanbuf[tid - off] : 0;
        __syncthreads();
        if (tid < NBMAX) scanbuf[tid] += t;
        __syncthreads();
    }
    if (tid < nb) {
        int cb = hist[tid];
        int start = scanbuf[tid] - cb;   // exclusive (position in buf)
        lofs[tid] = start;
        int g = (cb > 0) ? atomicAdd(&bfill[tid], cb) : 0;
        adj[tid] = tid * BCAP + g - start;  // buf idx -> tmp idx shift
    }
    __syncthreads();
#pragma unroll
    for (int k = 0; k < 8; ++k) {
        int l = tid + k * 256;
        if (l < cnt) {
            int b = ed[k] >> BK_SHIFT;
            int r = atomicAdd(&lofs[b], 1);
            buf[r] = make_uint2((unsigned)es[k], (unsigned)ed[k]);
            bkt_of[r] = (unsigned char)b;
        }
    }
    __syncthreads();
    for (int j = tid; j < cnt; j += 256) {
        int b = bkt_of[j];
        tmp[adj[b] + j] = buf[j];
    }
}

// Pass 2: one block per 512-node bucket. Per-node in-degree (LDS hist), local
// scan -> row_ptr, dis = rsqrt(deg+1), layer-0 pre-scale Z0 = dis*x, and the
// final edge scatter with LDS cursors. Everything stays inside one CU.
__global__ __launch_bounds__(512) void place2(const uint2* __restrict__ tmp,
                                              const int* __restrict__ bfill,
                                              const float* __restrict__ X,
                                              float* __restrict__ dis,
                                              int* __restrict__ row_ptr,
                                              int* __restrict__ edge_src,
                                              float* __restrict__ Z0, int kq,
                                              int n, int E, int nb) {
    __shared__ int hist[512];
    __shared__ int sc[512];
    __shared__ int sbf[NBMAX];
    __shared__ int bb_s;
    int b = blockIdx.x;
    int tid = threadIdx.x;
    if (tid < NBMAX) sbf[tid] = (tid < nb) ? bfill[tid] : 0;
    hist[tid] = 0;
    __syncthreads();
    if (tid == 0) {
        int s = 0;
        for (int k = 0; k < b; ++k) s += sbf[k];
        bb_s = s;
    }
    __syncthreads();
    int bb = bb_s;
    int cnt = sbf[b];
    const uint2* mybkt = tmp + (size_t)b * BCAP;
    int node0 = b << BK_SHIFT;
    for (int j = tid; j < cnt; j += 512)
        atomicAdd(&hist[(int)mybkt[j].y - node0], 1);
    __syncthreads();
    int v = hist[tid];
    sc[tid] = v;
    __syncthreads();
    for (int off = 1; off < 512; off <<= 1) {
        int t = (tid >= off) ? sc[tid - off] : 0;
        __syncthreads();
        sc[tid] += t;
        __syncthreads();
    }
    int excl = sc[tid] - v;
    int i = node0 + tid;
    if (i < n) {
        row_ptr[i] = bb + excl;
        float di = rsqrtf((float)(v + 1));  // +1: self-loop
        dis[i] = di;
        const float4* X4 = (const float4*)X;
        float4* Z4 = (float4*)Z0;
        for (int j = 0; j < kq; ++j) {
            float4 xv = X4[(size_t)i * kq + j];
            Z4[(size_t)i * kq + j] = make_float4(di * xv.x, di * xv.y, di * xv.z, di * xv.w);
        }
    }
    if (b == 0 && tid == 0) row_ptr[n] = E;
    __syncthreads();
    hist[tid] = bb + excl;  // reuse as LDS cursor
    __syncthreads();
    for (int j = tid; j < cnt; j += 512) {
        uint2 ev = mybkt[j];
        int pos = atomicAdd(&hist[(int)ev.y - node0], 1);
        edge_src[pos] = (int)ev.x;
    }
}

// fp32 wave-per-node aggregation (layer 0 path, 16-wide).
template <int LPN, int F4PL, int UNROLL>
__global__ __launch_bounds__(256) void agg_wave(const float* __restrict__ Z,
                                                const float* __restrict__ dis,
                                                const int* __restrict__ row_ptr,
                                                const int* __restrict__ edge_src,
                                                float* __restrict__ A, int n) {
    constexpr int GROUPS = 64 / LPN;
    constexpr int KQ = LPN * F4PL;  // float4 per node row
    int i = (blockIdx.x * 256 + threadIdx.x) >> 6;  // node = global wave id
    if (i >= n) return;
    int lane = threadIdx.x & 63;
    int g = lane / LPN;   // edge group
    int c = lane % LPN;   // feature lane
    const float4* Z4 = (const float4*)Z;
    float di = dis[i];
    size_t base = (size_t)i * KQ + c * F4PL;
    float4 acc[F4PL];
    if (g == 0) {
#pragma unroll
        for (int j = 0; j < F4PL; ++j) acc[j] = Z4[base + j];
    } else {
#pragma unroll
        for (int j = 0; j < F4PL; ++j) acc[j] = make_float4(0.f, 0.f, 0.f, 0.f);
    }
    int re0 = row_ptr[i], re1 = row_ptr[i + 1];
#pragma unroll UNROLL
    for (int e = re0 + g; e < re1; e += GROUPS) {
        int s = edge_src[e];
        size_t sb = (size_t)s * KQ + c * F4PL;
#pragma unroll
        for (int j = 0; j < F4PL; ++j) {
            float4 xs = Z4[sb + j];
            add4(acc[j], xs);
        }
    }
#pragma unroll
    for (int m = LPN; m < 64; m <<= 1) {
#pragma unroll
        for (int j = 0; j < F4PL; ++j) {
            acc[j].x += __shfl_xor(acc[j].x, m);
            acc[j].y += __shfl_xor(acc[j].y, m);
            acc[j].z += __shfl_xor(acc[j].z, m);
            acc[j].w += __shfl_xor(acc[j].w, m);
        }
    }
    if (g == 0) {
#pragma unroll
        for (int j = 0; j < F4PL; ++j) {
            float4 o = make_float4(di * acc[j].x, di * acc[j].y,
                                   di * acc[j].z, di * acc[j].w);
            ((float4*)A)[base + j] = o;
        }
    }
}

// fp16-input wave-per-node aggregation, 96-wide (layers 1-4):
//   A[i] = dis_i * ( sum_{s in in(i)} Zh_s + Zh_i ),  fp32 accumulate, fp32 out.
// 16 edge-groups x 4 feature lanes; each lane covers 24 halves = 3x uint4
// (dwordx4) loads per edge. Same 48 B/lane in flight as the winning fp32
// shape, but 2x edges per latency round and half the load instructions.
__global__ __launch_bounds__(256) void agg_wave_h(const __half* __restrict__ Zh,
                                                  const float* __restrict__ dis,
                                                  const int* __restrict__ row_ptr,
                                                  const int* __restrict__ edge_src,
                                                  float* __restrict__ A, int n) {
    int i = (blockIdx.x * 256 + threadIdx.x) >> 6;  // node = global wave id
    if (i >= n) return;
    int lane = threadIdx.x & 63;
    int g = lane >> 2;    // edge group 0-15
    int c = lane & 3;     // feature lane 0-3, covers halves [24c, 24c+24)
    float di = dis[i];
    float acc[24];
    if (g == 0) {  // self-loop term Zh_i
        const uint4* zp = (const uint4*)(Zh + (size_t)i * 96 + c * 24);
#pragma unroll
        for (int k = 0; k < 3; ++k) {
            uint4 u = zp[k];
            float2 f;
            f = __half22float2(*(const __half2*)&u.x); acc[k*8+0] = f.x; acc[k*8+1] = f.y;
            f = __half22float2(*(const __half2*)&u.y); acc[k*8+2] = f.x; acc[k*8+3] = f.y;
            f = __half22float2(*(const __half2*)&u.z); acc[k*8+4] = f.x; acc[k*8+5] = f.y;
            f = __half22float2(*(const __half2*)&u.w); acc[k*8+6] = f.x; acc[k*8+7] = f.y;
        }
    } else {
#pragma unroll
        for (int k = 0; k < 24; ++k) acc[k] = 0.f;
    }
    int re0 = row_ptr[i], re1 = row_ptr[i + 1];
#pragma unroll 2
    for (int e = re0 + g; e < re1; e += 16) {
        int s = edge_src[e];
        const uint4* zp = (const uint4*)(Zh + (size_t)s * 96 + c * 24);
        uint4 u0 = zp[0], u1 = zp[1], u2 = zp[2];
        float2 f;
        f = __half22float2(*(const __half2*)&u0.x); acc[0] += f.x;  acc[1] += f.y;
        f = __half22float2(*(const __half2*)&u0.y); acc[2] += f.x;  acc[3] += f.y;
        f = __half22float2(*(const __half2*)&u0.z); acc[4] += f.x;  acc[5] += f.y;
        f = __half22float2(*(const __half2*)&u0.w); acc[6] += f.x;  acc[7] += f.y;
        f = __half22float2(*(const __half2*)&u1.x); acc[8] += f.x;  acc[9] += f.y;
        f = __half22float2(*(const __half2*)&u1.y); acc[10] += f.x; acc[11] += f.y;
        f = __half22float2(*(const __half2*)&u1.z); acc[12] += f.x; acc[13] += f.y;
        f = __half22float2(*(const __half2*)&u1.w); acc[14] += f.x; acc[15] += f.y;
        f = __half22float2(*(const __half2*)&u2.x); acc[16] += f.x; acc[17] += f.y;
        f = __half22float2(*(const __half2*)&u2.y); acc[18] += f.x; acc[19] += f.y;
        f = __half22float2(*(const __half2*)&u2.z); acc[20] += f.x; acc[21] += f.y;
        f = __half22float2(*(const __half2*)&u2.w); acc[22] += f.x; acc[23] += f.y;
    }
    // Butterfly reduce across the 16 edge groups.
#pragma unroll
    for (int m = 4; m < 64; m <<= 1) {
#pragma unroll
        for (int k = 0; k < 24; ++k) acc[k] += __shfl_xor(acc[k], m);
    }
    if (g == 0) {
        float4* ap = (float4*)(A + (size_t)i * 96 + c * 24);
#pragma unroll
        for (int k = 0; k < 6; ++k)
            ap[k] = make_float4(di * acc[k * 4 + 0], di * acc[k * 4 + 1],
                                di * acc[k * 4 + 2], di * acc[k * 4 + 3]);
    }
}

// Xn[i,f] = leaky( sum_k A[i,k]*W[k,f] + b[f] ), optionally * dis[i].
// OUTH: write fp16 (next layer's pre-scaled Z); else fp32 (final H for pooling).
template <int K, bool SCALE, bool OUTH>
__global__ __launch_bounds__(192) void gemm_act_kernel(const float* __restrict__ A,
                                                       const float* __restrict__ W,
                                                       const float* __restrict__ b,
                                                       const float* __restrict__ dis,
                                                       void* __restrict__ Xn, int n) {
    constexpr int KQ = K / 4;
    __shared__ __align__(16) float4 Al[64 * KQ];
    int tid = threadIdx.x;
    int i0 = blockIdx.x * 64;
    for (int idx = tid; idx < 64 * KQ; idx += 192) {
        int gi = i0 + idx / KQ;
        Al[idx] = (gi < n) ? ((const float4*)A)[(size_t)i0 * KQ + idx]
                           : make_float4(0.f, 0.f, 0.f, 0.f);
    }
    __syncthreads();
    int fq = tid % 24;  // output float4 column
    int g = tid / 24;   // row group: rows g*8 .. g*8+7
    const float4* W4 = (const float4*)W;  // W4[k*24 + fq]
    float4 bb = ((const float4*)b)[fq];
    float4 acc[8];
#pragma unroll
    for (int r = 0; r < 8; ++r) acc[r] = bb;
    for (int kc = 0; kc < K; kc += 8) {
        float4 w[8];
#pragma unroll
        for (int kk = 0; kk < 8; ++kk) w[kk] = W4[(size_t)(kc + kk) * 24 + fq];
#pragma unroll
        for (int r = 0; r < 8; ++r) {
            const float4* ar = &Al[(g * 8 + r) * KQ + (kc >> 2)];
#pragma unroll
            for (int k4 = 0; k4 < 2; ++k4) {
                float4 a = ar[k4];
                float4 w0 = w[4 * k4 + 0], w1 = w[4 * k4 + 1];
                float4 w2 = w[4 * k4 + 2], w3 = w[4 * k4 + 3];
                acc[r].x += a.x * w0.x + a.y * w1.x + a.z * w2.x + a.w * w3.x;
                acc[r].y += a.x * w0.y + a.y * w1.y + a.z * w2.y + a.w * w3.y;
                acc[r].z += a.x * w0.z + a.y * w1.z + a.z * w2.z + a.w * w3.z;
                acc[r].w += a.x * w0.w + a.y * w1.w + a.z * w2.w + a.w * w3.w;
            }
        }
    }
#pragma unroll
    for (int r = 0; r < 8; ++r) {
        int gi = i0 + g * 8 + r;
        if (gi < n) {
            float4 o;
            o.x = LEAKY(acc[r].x); o.y = LEAKY(acc[r].y);
            o.z = LEAKY(acc[r].z); o.w = LEAKY(acc[r].w);
            if (SCALE) {
                float di = dis[gi];
                o.x *= di; o.y *= di; o.z *= di; o.w *= di;
            }
            if (OUTH) {
                __half2 h0 = __floats2half2_rn(o.x, o.y);
                __half2 h1 = __floats2half2_rn(o.z, o.w);
                uint2 u;
                u.x = *(unsigned*)&h0;
                u.y = *(unsigned*)&h1;
                ((uint2*)Xn)[(size_t)gi * 24 + fq] = u;
            } else {
                ((float4*)Xn)[(size_t)gi * 24 + fq] = o;
            }
        }
    }
}

__device__ __forceinline__ int lower_bound(const int* b, int n, int v) {
    int lo = 0, hi = n;
    while (lo < hi) {
        int m = (lo + hi) >> 1;
        if (b[m] < v) lo = m + 1; else hi = m;
    }
    return lo;
}

// grid = G*8, block = 96. Chunked per-graph partial max/sum.
__global__ void pool_partial(const float* __restrict__ X, const int* __restrict__ batch,
                             float* __restrict__ pmax, float* __restrict__ psum, int n) {
    int g = blockIdx.x / 8, ch = blockIdx.x % 8;
    int f = threadIdx.x;
    int s = lower_bound(batch, n, g), e = lower_bound(batch, n, g + 1);
    int len = e - s;
    int cs = s + (int)((long)len * ch / 8);
    int ce = s + (int)((long)len * (ch + 1) / 8);
    float mx = -INFINITY, sm = 0.f;
    for (int i = cs; i < ce; ++i) {
        float v = X[(size_t)i * 96 + f];
        mx = fmaxf(mx, v);
        sm += v;
    }
    pmax[(size_t)blockIdx.x * 96 + f] = mx;
    psum[(size_t)blockIdx.x * 96 + f] = sm;
}

// Merged pool_reduce + MLP head: grid = G, block = 96.
__global__ void pool_final(const float* __restrict__ pmax, const float* __restrict__ psum,
                           const int* __restrict__ batch,
                           const float* __restrict__ Wo1, const float* __restrict__ bo1,
                           const float* __restrict__ Wo2, const float* __restrict__ bo2,
                           float* __restrict__ out, int n) {
    __shared__ float pooled[192];
    __shared__ float sh[96];
    int g = blockIdx.x, f = threadIdx.x;
    float mx = -INFINITY, sm = 0.f;
    for (int c = 0; c < 8; ++c) {
        mx = fmaxf(mx, pmax[(size_t)(g * 8 + c) * 96 + f]);
        sm += psum[(size_t)(g * 8 + c) * 96 + f];
    }
    int s = lower_bound(batch, n, g), e = lower_bound(batch, n, g + 1);
    float cnt = fmaxf((float)(e - s), 1.f);
    pooled[f] = mx;
    pooled[96 + f] = sm / cnt;
    __syncthreads();
    float acc = bo1[f];
    for (int k = 0; k < 192; ++k) acc += pooled[k] * Wo1[k * 96 + f];
    float a = LEAKY(acc);
    sh[f] = a * Wo2[f];
    __syncthreads();
    if (f == 0) {
        float sacc = 0.f;
        for (int k = 0; k < 96; ++k) sacc += sh[k];
        out[g] = sacc + bo2[0];
    }
}

extern "C" void kernel_launch(void* const* d_in, const int* in_sizes, int n_in,
                              void* d_out, int out_size, void* d_ws, size_t ws_size,
                              hipStream_t stream) {
    const float* x      = (const float*)d_in[0];
    const int*   eidx   = (const int*)d_in[1];
    const int*   batch  = (const int*)d_in[2];
    const float* W_init = (const float*)d_in[3];
    const float* b_init = (const float*)d_in[4];
    const float* W1 = (const float*)d_in[5];  const float* b1 = (const float*)d_in[6];
    const float* W2 = (const float*)d_in[7];  const float* b2 = (const float*)d_in[8];
    const float* W3 = (const float*)d_in[9];  const float* b3 = (const float*)d_in[10];
    const float* W4 = (const float*)d_in[11]; const float* b4 = (const float*)d_in[12];
    const float* Wo1 = (const float*)d_in[13]; const float* bo1 = (const float*)d_in[14];
    const float* Wo2 = (const float*)d_in[15]; const float* bo2 = (const float*)d_in[16];
    float* out = (float*)d_out;

    const int N = in_sizes[2];
    const int E = in_sizes[1] / 2;
    const int G = out_size;
    const int* src = eidx;
    const int* dst = eidx + E;

    char* ws = (char*)d_ws;
    size_t off = 0;
    auto alloc = [&](size_t bytes) {
        size_t o = off;
        off += (bytes + 255) & ~(size_t)255;
        return o;
    };
    float* dis       = (float*)(ws + alloc((size_t)N * 4));
    int*   row_ptr   = (int*)(ws + alloc((size_t)(N + 1) * 4));
    int*   bfill     = (int*)(ws + alloc(NBMAX * 4));
    int*   edge_src  = (int*)(ws + alloc((size_t)E * 4));
    float* Z0        = (float*)(ws + alloc((size_t)N * 16 * 4));
    __half* ZA       = (__half*)(ws + alloc((size_t)N * 96 * 2));
    __half* ZB       = (__half*)(ws + alloc((size_t)N * 96 * 2));
    float* H         = (float*)(ws + alloc((size_t)N * 96 * 4));
    float* Agg       = (float*)(ws + alloc((size_t)N * 96 * 4));
    float* pmax      = (float*)(ws + alloc((size_t)G * 8 * 96 * 4));
    float* psum      = (float*)(ws + alloc((size_t)G * 8 * 96 * 4));
    uint2* tmp       = (uint2*)Agg;  // 12.8 MB < 19.2 MB; bin/place2 end before agg0
    (void)ws_size; (void)n_in;

    const int nbBkt  = (N + (1 << BK_SHIFT) - 1) >> BK_SHIFT;
    const int nbWave = (N + 3) / 4;       // 4 nodes (waves) per 256-thread block
    const int nbTile = (N + 63) / 64;

    hipMemsetAsync(bfill, 0, NBMAX * 4, stream);
    bin_kernel<<<(E + 2047) / 2048, 256, 0, stream>>>(src, dst, bfill, tmp, E, nbBkt);
    place2<<<nbBkt, 512, 0, stream>>>(tmp, bfill, x, dis, row_ptr, edge_src, Z0,
                                      4, N, E, nbBkt);

    // Layer 0: fp32 agg of pre-scaled 16-wide input, then 16x96 GEMM -> fp16 Z1.
    agg_wave<4, 1, 2><<<nbWave, 256, 0, stream>>>(Z0, dis, row_ptr, edge_src, Agg, N);
    gemm_act_kernel<16, true, true><<<nbTile, 192, 0, stream>>>(Agg, W_init, b_init,
                                                                dis, ZA, N);

    const float* Ws[4] = {W1, W2, W3, W4};
    const float* bs[4] = {b1, b2, b3, b4};
    __half* cur = ZA;
    __half* nxt = ZB;
    for (int l = 0; l < 4; ++l) {
        agg_wave_h<<<nbWave, 256, 0, stream>>>(cur, dis, row_ptr, edge_src, Agg, N);
        if (l < 3) {
            gemm_act_kernel<96, true, true><<<nbTile, 192, 0, stream>>>(Agg, Ws[l], bs[l],
                                                                        dis, nxt, N);
            __half* t = cur; cur = nxt; nxt = t;
        } else {  // last layer: fp32 unscaled H for pooling
            gemm_act_kernel<96, false, false><<<nbTile, 192, 0, stream>>>(Agg, Ws[l], bs[l],
                                                                          dis, H, N);
        }
    }

    pool_partial<<<G * 8, 96, 0, stream>>>(H, batch, pmax, psum, N);
    pool_final<<<G, 96, 0, stream>>>(pmax, psum, batch, Wo1, bo1, Wo2, bo2, out, N);
}

// Round 16
// 380.809 us; speedup vs baseline: 1.6430x; 1.2616x over previous
//
#include <hip/hip_runtime.h>
#include <hip/hip_fp16.h>
#include <math.h>

#define LEAKY(x) ((x) > 0.f ? (x) : 0.01f * (x))
#define BK_SHIFT 9            // 512 nodes per bucket
#define NBMAX 128             // supports N <= 65536
#define BCAP 16384            // edges capacity per bucket (mean 8192 + ~90 sigma)

typedef _Float16 half8 __attribute__((ext_vector_type(8)));
typedef float f32x4 __attribute__((ext_vector_type(4)));

__device__ __forceinline__ void add4(float4& acc, const float4& v) {
    acc.x += v.x; acc.y += v.y; acc.z += v.z; acc.w += v.w;
}

// Pass 1 of CSR fill: LDS counting-sort 2048-edge chunks by 512-node bucket,
// reserve per-bucket spans via bfill atomics, flush contiguous runs to tmp
// (fixed-capacity bucket-major: bucket b owns tmp[b*BCAP .. b*BCAP+BCAP)).
__global__ __launch_bounds__(256) void bin_kernel(const int* __restrict__ src,
                                                  const int* __restrict__ dst,
                                                  int* __restrict__ bfill,
                                                  uint2* __restrict__ tmp,
                                                  int E, int nb) {
    __shared__ int hist[NBMAX];
    __shared__ int scanbuf[NBMAX];
    __shared__ int lofs[NBMAX];
    __shared__ int adj[NBMAX];
    __shared__ uint2 buf[2048];
    __shared__ unsigned char bkt_of[2048];
    int base = blockIdx.x * 2048;
    int cnt = min(2048, E - base);
    int tid = threadIdx.x;
    for (int b = tid; b < NBMAX; b += 256) hist[b] = 0;
    __syncthreads();
    int es[8], ed[8];
#pragma unroll
    for (int k = 0; k < 8; ++k) {
        int l = tid + k * 256;
        if (l < cnt) {
            es[k] = src[base + l];
            ed[k] = dst[base + l];
            atomicAdd(&hist[ed[k] >> BK_SHIFT], 1);
        }
    }
    __syncthreads();
    if (tid < NBMAX) scanbuf[tid] = hist[tid];
    __syncthreads();
    for (int off = 1; off < NBMAX; off <<= 1) {
        int t = (tid < NBMAX && tid >= off) ? scanbuf[tid - off] : 0;
        __syncthreads();
        if (tid < NBMAX) scanbuf[tid] += t;
        __syncthreads();
    }
    if (tid < nb) {
        int cb = hist[tid];
        int start = scanbuf[tid] - cb;   // exclusive (position in buf)
        lofs[tid] = start;
        int g = (cb > 0) ? atomicAdd(&bfill[tid], cb) : 0;
        adj[tid] = tid * BCAP + g - start;  // buf idx -> tmp idx shift
    }
    __syncthreads();
#pragma unroll
    for (int k = 0; k < 8; ++k) {
        int l = tid + k * 256;
        if (l < cnt) {
            int b = ed[k] >> BK_SHIFT;
            int r = atomicAdd(&lofs[b], 1);
            buf[r] = make_uint2((unsigned)es[k], (unsigned)ed[k]);
            bkt_of[r] = (unsigned char)b;
        }
    }
    __syncthreads();
    for (int j = tid; j < cnt; j += 256) {
        int b = bkt_of[j];
        tmp[adj[b] + j] = buf[j];
    }
}

// Pass 2: one block per 512-node bucket. Per-node in-degree (LDS hist), local
// scan -> row_ptr, dis = rsqrt(deg+1), layer-0 pre-scale Z0 = dis*x, and the
// final edge scatter with LDS cursors. Everything stays inside one CU.
__global__ __launch_bounds__(512) void place2(const uint2* __restrict__ tmp,
                                              const int* __restrict__ bfill,
                                              const float* __restrict__ X,
                                              float* __restrict__ dis,
                                              int* __restrict__ row_ptr,
                                              int* __restrict__ edge_src,
                                              float* __restrict__ Z0, int kq,
                                              int n, int E, int nb) {
    __shared__ int hist[512];
    __shared__ int sc[512];
    __shared__ int sbf[NBMAX];
    __shared__ int bb_s;
    int b = blockIdx.x;
    int tid = threadIdx.x;
    if (tid < NBMAX) sbf[tid] = (tid < nb) ? bfill[tid] : 0;
    hist[tid] = 0;
    __syncthreads();
    if (tid == 0) {
        int s = 0;
        for (int k = 0; k < b; ++k) s += sbf[k];
        bb_s = s;
    }
    __syncthreads();
    int bb = bb_s;
    int cnt = sbf[b];
    const uint2* mybkt = tmp + (size_t)b * BCAP;
    int node0 = b << BK_SHIFT;
    for (int j = tid; j < cnt; j += 512)
        atomicAdd(&hist[(int)mybkt[j].y - node0], 1);
    __syncthreads();
    int v = hist[tid];
    sc[tid] = v;
    __syncthreads();
    for (int off = 1; off < 512; off <<= 1) {
        int t = (tid >= off) ? sc[tid - off] : 0;
        __syncthreads();
        sc[tid] += t;
        __syncthreads();
    }
    int excl = sc[tid] - v;
    int i = node0 + tid;
    if (i < n) {
        row_ptr[i] = bb + excl;
        float di = rsqrtf((float)(v + 1));  // +1: self-loop
        dis[i] = di;
        const float4* X4 = (const float4*)X;
        float4* Z4 = (float4*)Z0;
        for (int j = 0; j < kq; ++j) {
            float4 xv = X4[(size_t)i * kq + j];
            Z4[(size_t)i * kq + j] = make_float4(di * xv.x, di * xv.y, di * xv.z, di * xv.w);
        }
    }
    if (b == 0 && tid == 0) row_ptr[n] = E;
    __syncthreads();
    hist[tid] = bb + excl;  // reuse as LDS cursor
    __syncthreads();
    for (int j = tid; j < cnt; j += 512) {
        uint2 ev = mybkt[j];
        int pos = atomicAdd(&hist[(int)ev.y - node0], 1);
        edge_src[pos] = (int)ev.x;
    }
}

// fp32 wave-per-node aggregation (layer 0 path, 16-wide).
template <int LPN, int F4PL, int UNROLL>
__global__ __launch_bounds__(256) void agg_wave(const float* __restrict__ Z,
                                                const float* __restrict__ dis,
                                                const int* __restrict__ row_ptr,
                                                const int* __restrict__ edge_src,
                                                float* __restrict__ A, int n) {
    constexpr int GROUPS = 64 / LPN;
    constexpr int KQ = LPN * F4PL;  // float4 per node row
    int i = (blockIdx.x * 256 + threadIdx.x) >> 6;  // node = global wave id
    if (i >= n) return;
    int lane = threadIdx.x & 63;
    int g = lane / LPN;   // edge group
    int c = lane % LPN;   // feature lane
    const float4* Z4 = (const float4*)Z;
    float di = dis[i];
    size_t base = (size_t)i * KQ + c * F4PL;
    float4 acc[F4PL];
    if (g == 0) {
#pragma unroll
        for (int j = 0; j < F4PL; ++j) acc[j] = Z4[base + j];
    } else {
#pragma unroll
        for (int j = 0; j < F4PL; ++j) acc[j] = make_float4(0.f, 0.f, 0.f, 0.f);
    }
    int re0 = row_ptr[i], re1 = row_ptr[i + 1];
#pragma unroll UNROLL
    for (int e = re0 + g; e < re1; e += GROUPS) {
        int s = edge_src[e];
        size_t sb = (size_t)s * KQ + c * F4PL;
#pragma unroll
        for (int j = 0; j < F4PL; ++j) {
            float4 xs = Z4[sb + j];
            add4(acc[j], xs);
        }
    }
#pragma unroll
    for (int m = LPN; m < 64; m <<= 1) {
#pragma unroll
        for (int j = 0; j < F4PL; ++j) {
            acc[j].x += __shfl_xor(acc[j].x, m);
            acc[j].y += __shfl_xor(acc[j].y, m);
            acc[j].z += __shfl_xor(acc[j].z, m);
            acc[j].w += __shfl_xor(acc[j].w, m);
        }
    }
    if (g == 0) {
#pragma unroll
        for (int j = 0; j < F4PL; ++j) {
            float4 o = make_float4(di * acc[j].x, di * acc[j].y,
                                   di * acc[j].z, di * acc[j].w);
            ((float4*)A)[base + j] = o;
        }
    }
}

// fp16-input wave-per-node aggregation, 96-wide (layers 1-4): R13 measured-best
// shape — 8 edge-groups x 8 feature lanes x 12 halves (3x uint2), unroll 4.
// Accumulator footprint 12 floats/lane: proven to keep 3 loads in flight
// (24-float variants serialize — R10/R15 regressions).
__global__ __launch_bounds__(256) void agg_wave_h(const __half* __restrict__ Zh,
                                                  const float* __restrict__ dis,
                                                  const int* __restrict__ row_ptr,
                                                  const int* __restrict__ edge_src,
                                                  float* __restrict__ A, int n) {
    int i = (blockIdx.x * 256 + threadIdx.x) >> 6;  // node = global wave id
    if (i >= n) return;
    int lane = threadIdx.x & 63;
    int g = lane >> 3;    // edge group 0-7
    int c = lane & 7;     // feature lane 0-7, covers halves [12c, 12c+12)
    float di = dis[i];
    float acc[12];
    if (g == 0) {  // self-loop term Zh_i
        const uint2* zp = (const uint2*)(Zh + (size_t)i * 96 + c * 12);
#pragma unroll
        for (int k = 0; k < 3; ++k) {
            uint2 u = zp[k];
            float2 f0 = __half22float2(*(const __half2*)&u.x);
            float2 f1 = __half22float2(*(const __half2*)&u.y);
            acc[k * 4 + 0] = f0.x; acc[k * 4 + 1] = f0.y;
            acc[k * 4 + 2] = f1.x; acc[k * 4 + 3] = f1.y;
        }
    } else {
#pragma unroll
        for (int k = 0; k < 12; ++k) acc[k] = 0.f;
    }
    int re0 = row_ptr[i], re1 = row_ptr[i + 1];
#pragma unroll 4
    for (int e = re0 + g; e < re1; e += 8) {
        int s = edge_src[e];
        const uint2* zp = (const uint2*)(Zh + (size_t)s * 96 + c * 12);
        uint2 u0 = zp[0], u1 = zp[1], u2 = zp[2];
        float2 f;
        f = __half22float2(*(const __half2*)&u0.x); acc[0] += f.x; acc[1] += f.y;
        f = __half22float2(*(const __half2*)&u0.y); acc[2] += f.x; acc[3] += f.y;
        f = __half22float2(*(const __half2*)&u1.x); acc[4] += f.x; acc[5] += f.y;
        f = __half22float2(*(const __half2*)&u1.y); acc[6] += f.x; acc[7] += f.y;
        f = __half22float2(*(const __half2*)&u2.x); acc[8] += f.x; acc[9] += f.y;
        f = __half22float2(*(const __half2*)&u2.y); acc[10] += f.x; acc[11] += f.y;
    }
    // Butterfly reduce across the 8 edge groups.
#pragma unroll
    for (int m = 8; m < 64; m <<= 1) {
#pragma unroll
        for (int k = 0; k < 12; ++k) acc[k] += __shfl_xor(acc[k], m);
    }
    if (g == 0) {
        float4* ap = (float4*)(A + (size_t)i * 96 + c * 12);
#pragma unroll
        for (int k = 0; k < 3; ++k)
            ap[k] = make_float4(di * acc[k * 4 + 0], di * acc[k * 4 + 1],
                                di * acc[k * 4 + 2], di * acc[k * 4 + 3]);
    }
}

// MFMA GEMM (96x96, fp16 operands, fp32 accum):
//   Xn[i,f] = leaky( sum_k Agg[i,k]*W[k,f] + b[f] ) (* dis[i] if SCALE)
// 64 nodes/block, 256 thr = 4 waves; wave w owns rows w*16..w*16+15.
// Ah: Agg tile fp16 row-major, padded stride 104 halves (bank spread).
// Wt: W transposed fp16 [n][k] stride 104 -> B-fragments contiguous (b128).
// Fragment layouts (HW-verified, docs §3): A[m=lane&15][k=quad*8+j],
// B[k=quad*8+j][n=lane&15], D col=lane&15 row=quad*4+reg.
template <bool SCALE, bool OUTH>
__global__ __launch_bounds__(256) void gemm_mfma(const float* __restrict__ A,
                                                 const float* __restrict__ W,
                                                 const float* __restrict__ b,
                                                 const float* __restrict__ dis,
                                                 void* __restrict__ Xn, int n) {
    constexpr int LDA = 104;
    __shared__ __align__(16) _Float16 Ah[64 * LDA];
    __shared__ __align__(16) _Float16 Wt[96 * LDA];
    int tid = threadIdx.x;
    int i0 = blockIdx.x * 64;
    for (int idx = tid; idx < 64 * 24; idx += 256) {
        int r = idx / 24, c4 = idx % 24;
        int gi = i0 + r;
        float4 v = (gi < n) ? ((const float4*)A)[(size_t)gi * 24 + c4]
                            : make_float4(0.f, 0.f, 0.f, 0.f);
        _Float16* p = &Ah[r * LDA + c4 * 4];
        p[0] = (_Float16)v.x; p[1] = (_Float16)v.y;
        p[2] = (_Float16)v.z; p[3] = (_Float16)v.w;
    }
    for (int idx = tid; idx < 96 * 24; idx += 256) {
        int k = idx / 24, c4 = idx % 24;
        float4 v = ((const float4*)W)[(size_t)k * 24 + c4];
        int nc = c4 * 4;
        Wt[(nc + 0) * LDA + k] = (_Float16)v.x;
        Wt[(nc + 1) * LDA + k] = (_Float16)v.y;
        Wt[(nc + 2) * LDA + k] = (_Float16)v.z;
        Wt[(nc + 3) * LDA + k] = (_Float16)v.w;
    }
    __syncthreads();
    int w = tid >> 6, lane = tid & 63;
    int q = lane >> 4, c = lane & 15;
    half8 af[3];
#pragma unroll
    for (int kc = 0; kc < 3; ++kc)
        af[kc] = *(const half8*)&Ah[(w * 16 + c) * LDA + kc * 32 + q * 8];
    // rows this lane writes (same for every n-tile): w*16 + q*4 + r
    float dvals[4];
#pragma unroll
    for (int r = 0; r < 4; ++r) {
        int gi = i0 + w * 16 + q * 4 + r;
        dvals[r] = (SCALE && gi < n) ? dis[gi] : 1.f;
    }
#pragma unroll
    for (int nt = 0; nt < 6; ++nt) {
        f32x4 acc = {0.f, 0.f, 0.f, 0.f};
#pragma unroll
        for (int kc = 0; kc < 3; ++kc) {
            half8 bf = *(const half8*)&Wt[(nt * 16 + c) * LDA + kc * 32 + q * 8];
            acc = __builtin_amdgcn_mfma_f32_16x16x32_f16(af[kc], bf, acc, 0, 0, 0);
        }
        int col = nt * 16 + c;
        float bias = b[col];
#pragma unroll
        for (int r = 0; r < 4; ++r) {
            int gi = i0 + w * 16 + q * 4 + r;
            if (gi < n) {
                float v = acc[r] + bias;
                v = LEAKY(v);
                if (SCALE) v *= dvals[r];
                if (OUTH)
                    ((_Float16*)Xn)[(size_t)gi * 96 + col] = (_Float16)v;
                else
                    ((float*)Xn)[(size_t)gi * 96 + col] = v;
            }
        }
    }
}

// VALU GEMM for layer 0 (K=16): Xn = leaky(A@W + b) * dis, fp16 out.
__global__ __launch_bounds__(192) void gemm_l0(const float* __restrict__ A,
                                               const float* __restrict__ W,
                                               const float* __restrict__ b,
                                               const float* __restrict__ dis,
                                               __half* __restrict__ Xn, int n) {
    constexpr int KQ = 4;
    __shared__ __align__(16) float4 Al[64 * KQ];
    int tid = threadIdx.x;
    int i0 = blockIdx.x * 64;
    for (int idx = tid; idx < 64 * KQ; idx += 192) {
        int gi = i0 + idx / KQ;
        Al[idx] = (gi < n) ? ((const float4*)A)[(size_t)i0 * KQ + idx]
                           : make_float4(0.f, 0.f, 0.f, 0.f);
    }
    __syncthreads();
    int fq = tid % 24;
    int g = tid / 24;
    const float4* W4 = (const float4*)W;
    float4 bb = ((const float4*)b)[fq];
    float4 acc[8];
#pragma unroll
    for (int r = 0; r < 8; ++r) acc[r] = bb;
    for (int kc = 0; kc < 16; kc += 8) {
        float4 w[8];
#pragma unroll
        for (int kk = 0; kk < 8; ++kk) w[kk] = W4[(size_t)(kc + kk) * 24 + fq];
#pragma unroll
        for (int r = 0; r < 8; ++r) {
            const float4* ar = &Al[(g * 8 + r) * KQ + (kc >> 2)];
#pragma unroll
            for (int k4 = 0; k4 < 2; ++k4) {
                float4 a = ar[k4];
                float4 w0 = w[4 * k4 + 0], w1 = w[4 * k4 + 1];
                float4 w2 = w[4 * k4 + 2], w3 = w[4 * k4 + 3];
                acc[r].x += a.x * w0.x + a.y * w1.x + a.z * w2.x + a.w * w3.x;
                acc[r].y += a.x * w0.y + a.y * w1.y + a.z * w2.y + a.w * w3.y;
                acc[r].z += a.x * w0.z + a.y * w1.z + a.z * w2.z + a.w * w3.z;
                acc[r].w += a.x * w0.w + a.y * w1.w + a.z * w2.w + a.w * w3.w;
            }
        }
    }
#pragma unroll
    for (int r = 0; r < 8; ++r) {
        int gi = i0 + g * 8 + r;
        if (gi < n) {
            float di = dis[gi];
            float4 o;
            o.x = di * LEAKY(acc[r].x); o.y = di * LEAKY(acc[r].y);
            o.z = di * LEAKY(acc[r].z); o.w = di * LEAKY(acc[r].w);
            __half2 h0 = __floats2half2_rn(o.x, o.y);
            __half2 h1 = __floats2half2_rn(o.z, o.w);
            uint2 u;
            u.x = *(unsigned*)&h0;
            u.y = *(unsigned*)&h1;
            ((uint2*)Xn)[(size_t)gi * 24 + fq] = u;
        }
    }
}

__device__ __forceinline__ int lower_bound(const int* b, int n, int v) {
    int lo = 0, hi = n;
    while (lo < hi) {
        int m = (lo + hi) >> 1;
        if (b[m] < v) lo = m + 1; else hi = m;
    }
    return lo;
}

// grid = G*8, block = 96. Chunked per-graph partial max/sum.
__global__ void pool_partial(const float* __restrict__ X, const int* __restrict__ batch,
                             float* __restrict__ pmax, float* __restrict__ psum, int n) {
    int g = blockIdx.x / 8, ch = blockIdx.x % 8;
    int f = threadIdx.x;
    int s = lower_bound(batch, n, g), e = lower_bound(batch, n, g + 1);
    int len = e - s;
    int cs = s + (int)((long)len * ch / 8);
    int ce = s + (int)((long)len * (ch + 1) / 8);
    float mx = -INFINITY, sm = 0.f;
    for (int i = cs; i < ce; ++i) {
        float v = X[(size_t)i * 96 + f];
        mx = fmaxf(mx, v);
        sm += v;
    }
    pmax[(size_t)blockIdx.x * 96 + f] = mx;
    psum[(size_t)blockIdx.x * 96 + f] = sm;
}

// Merged pool_reduce + MLP head: grid = G, block = 96.
__global__ void pool_final(const float* __restrict__ pmax, const float* __restrict__ psum,
                           const int* __restrict__ batch,
                           const float* __restrict__ Wo1, const float* __restrict__ bo1,
                           const float* __restrict__ Wo2, const float* __restrict__ bo2,
                           float* __restrict__ out, int n) {
    __shared__ float pooled[192];
    __shared__ float sh[96];
    int g = blockIdx.x, f = threadIdx.x;
    float mx = -INFINITY, sm = 0.f;
    for (int c = 0; c < 8; ++c) {
        mx = fmaxf(mx, pmax[(size_t)(g * 8 + c) * 96 + f]);
        sm += psum[(size_t)(g * 8 + c) * 96 + f];
    }
    int s = lower_bound(batch, n, g), e = lower_bound(batch, n, g + 1);
    float cnt = fmaxf((float)(e - s), 1.f);
    pooled[f] = mx;
    pooled[96 + f] = sm / cnt;
    __syncthreads();
    float acc = bo1[f];
    for (int k = 0; k < 192; ++k) acc += pooled[k] * Wo1[k * 96 + f];
    float a = LEAKY(acc);
    sh[f] = a * Wo2[f];
    __syncthreads();
    if (f == 0) {
        float sacc = 0.f;
        for (int k = 0; k < 96; ++k) sacc += sh[k];
        out[g] = sacc + bo2[0];
    }
}

extern "C" void kernel_launch(void* const* d_in, const int* in_sizes, int n_in,
                              void* d_out, int out_size, void* d_ws, size_t ws_size,
                              hipStream_t stream) {
    const float* x      = (const float*)d_in[0];
    const int*   eidx   = (const int*)d_in[1];
    const int*   batch  = (const int*)d_in[2];
    const float* W_init = (const float*)d_in[3];
    const float* b_init = (const float*)d_in[4];
    const float* W1 = (const float*)d_in[5];  const float* b1 = (const float*)d_in[6];
    const float* W2 = (const float*)d_in[7];  const float* b2 = (const float*)d_in[8];
    const float* W3 = (const float*)d_in[9];  const float* b3 = (const float*)d_in[10];
    const float* W4 = (const float*)d_in[11]; const float* b4 = (const float*)d_in[12];
    const float* Wo1 = (const float*)d_in[13]; const float* bo1 = (const float*)d_in[14];
    const float* Wo2 = (const float*)d_in[15]; const float* bo2 = (const float*)d_in[16];
    float* out = (float*)d_out;

    const int N = in_sizes[2];
    const int E = in_sizes[1] / 2;
    const int G = out_size;
    const int* src = eidx;
    const int* dst = eidx + E;

    char* ws = (char*)d_ws;
    size_t off = 0;
    auto alloc = [&](size_t bytes) {
        size_t o = off;
        off += (bytes + 255) & ~(size_t)255;
        return o;
    };
    float* dis       = (float*)(ws + alloc((size_t)N * 4));
    int*   row_ptr   = (int*)(ws + alloc((size_t)(N + 1) * 4));
    int*   bfill     = (int*)(ws + alloc(NBMAX * 4));
    int*   edge_src  = (int*)(ws + alloc((size_t)E * 4));
    float* Z0        = (float*)(ws + alloc((size_t)N * 16 * 4));
    __half* ZA       = (__half*)(ws + alloc((size_t)N * 96 * 2));
    __half* ZB       = (__half*)(ws + alloc((size_t)N * 96 * 2));
    float* H         = (float*)(ws + alloc((size_t)N * 96 * 4));
    float* Agg       = (float*)(ws + alloc((size_t)N * 96 * 4));
    float* pmax      = (float*)(ws + alloc((size_t)G * 8 * 96 * 4));
    float* psum      = (float*)(ws + alloc((size_t)G * 8 * 96 * 4));
    uint2* tmp       = (uint2*)Agg;  // 12.8 MB < 19.2 MB; bin/place2 end before agg0
    (void)ws_size; (void)n_in;

    const int nbBkt  = (N + (1 << BK_SHIFT) - 1) >> BK_SHIFT;
    const int nbWave = (N + 3) / 4;       // 4 nodes (waves) per 256-thread block
    const int nbTile = (N + 63) / 64;

    hipMemsetAsync(bfill, 0, NBMAX * 4, stream);
    bin_kernel<<<(E + 2047) / 2048, 256, 0, stream>>>(src, dst, bfill, tmp, E, nbBkt);
    place2<<<nbBkt, 512, 0, stream>>>(tmp, bfill, x, dis, row_ptr, edge_src, Z0,
                                      4, N, E, nbBkt);

    // Layer 0: fp32 agg of pre-scaled 16-wide input, then 16x96 VALU GEMM -> fp16 Z1.
    agg_wave<4, 1, 2><<<nbWave, 256, 0, stream>>>(Z0, dis, row_ptr, edge_src, Agg, N);
    gemm_l0<<<nbTile, 192, 0, stream>>>(Agg, W_init, b_init, dis, ZA, N);

    const float* Ws[4] = {W1, W2, W3, W4};
    const float* bs[4] = {b1, b2, b3, b4};
    __half* cur = ZA;
    __half* nxt = ZB;
    for (int l = 0; l < 4; ++l) {
        agg_wave_h<<<nbWave, 256, 0, stream>>>(cur, dis, row_ptr, edge_src, Agg, N);
        if (l < 3) {
            gemm_mfma<true, true><<<nbTile, 256, 0, stream>>>(Agg, Ws[l], bs[l],
                                                              dis, nxt, N);
            __half* t = cur; cur = nxt; nxt = t;
        } else {  // last layer: fp32 unscaled H for pooling
            gemm_mfma<false, false><<<nbTile, 256, 0, stream>>>(Agg, Ws[l], bs[l],
                                                                dis, H, N);
        }
    }

    pool_partial<<<G * 8, 96, 0, stream>>>(H, batch, pmax, psum, N);
    pool_final<<<G, 96, 0, stream>>>(pmax, psum, batch, Wo1, bo1, Wo2, bo2, out, N);
}